// Round 2
// baseline (79.098 us; speedup 1.0000x reference)
//
#include <hip/hip_runtime.h>
#include <math.h>

#define DIM 64
#define BATCH 4096

// clang-native vector type (true vector-of-scalars, 16 B stores)
typedef float vf4 __attribute__((ext_vector_type(4)));

// TWO waves per batch element (R2: was one). Closed-form amplitudes of
// psi = D(alpha) S(r) |0>:
//   psi_{n+1} = (alpha*(1+tanh r)*psi_n - tanh r*sqrt(n)*psi_{n-1}) / sqrt(n+1)
// All 64 lanes run the 63-step recurrence redundantly (wave-uniform VALU,
// ~750 cycles, no shuffles in the chain); lane n latches psi_n. Butterfly-
// normalize, then each wave writes HALF the rows of rho[b] = psi psi^T
// (imag exactly 0 -> real-only float buffer per R1 fault probe).
//
// R2 changes vs the 77.7us kernel:
//  - grid 1024->2048 blocks (8 blocks/CU, 32 waves/CU = max occupancy;
//    was 16/32). Each wave stores 32 rows (8 x 1KB instructions).
//  - plain stores instead of __builtin_nontemporal_store: the harness fill
//    kernel sustains 5.9 TB/s through the normal store path; NT buys nothing
//    for full-line streaming writes and is the remaining policy difference.
__global__ __launch_bounds__(256) void qencoder_kernel(const float* __restrict__ x,
                                                       float* __restrict__ out,
                                                       int interleaved) {
    const int lane = threadIdx.x & 63;
    const int gw = blockIdx.x * (blockDim.x >> 6) + (threadIdx.x >> 6);  // global wave
    const int b = gw >> 1;        // batch element
    const int half = gw & 1;      // which 32-row half this wave stores

    const float TANH_R = 0.46211715726f;   // tanh(0.5)
    const float alpha = 0.5f * x[b];
    const float c1 = alpha * (1.0f + TANH_R);   // alpha * e^r / cosh r

    // 63-step recurrence, fully unrolled (sqrt(n), rsqrt(n+1) fold to literals)
    float pm1 = 1.0f;           // psi_{n-1} -> starts as psi_0
    float p   = c1;             // psi_1 = c1 * psi_0
    float v = (lane == 0) ? 1.0f : 0.0f;
    if (lane == 1) v = p;
    #pragma unroll
    for (int n = 1; n < DIM - 1; ++n) {
        float pn = (c1 * p - TANH_R * sqrtf((float)n) * pm1) * rsqrtf((float)(n + 1));
        pm1 = p;
        p = pn;
        if (lane == n + 1) v = pn;
    }

    // normalize
    float n2 = v * v;
    #pragma unroll
    for (int off = 32; off; off >>= 1) n2 += __shfl_xor(n2, off, 64);
    v *= rsqrtf(n2);

    if (interleaved) {
        // complex64: (re, im) pairs, im = 0. vf4 = 2 complex elements.
        // (defensive path — evidence says out is real-only)
        const int cp = lane & 31;
        const int rs = lane >> 5;
        float pc0 = __shfl(v, 2 * cp, 64);
        float pc1 = __shfl(v, 2 * cp + 1, 64);
        vf4* o4 = (vf4*)out + (size_t)b * (DIM * DIM / 2);
        #pragma unroll
        for (int i = 0; i < DIM / 4; ++i) {
            int ii = half * (DIM / 4) + i;     // this wave's 16 row-pairs
            int row = 2 * ii + rs;
            float vr = __shfl(v, row, 64);
            vf4 val = {vr * pc0, 0.f, vr * pc1, 0.f};
            o4[row * (DIM / 2) + cp] = val;
        }
    } else {
        // real-only float buffer: lane covers cols [4c,4c+4) of row 4*ii+rq
        const int c  = lane & 15;
        const int rq = lane >> 4;
        float pc0 = __shfl(v, 4 * c + 0, 64);
        float pc1 = __shfl(v, 4 * c + 1, 64);
        float pc2 = __shfl(v, 4 * c + 2, 64);
        float pc3 = __shfl(v, 4 * c + 3, 64);
        vf4* o4 = (vf4*)out + (size_t)b * (DIM * DIM / 4);
        #pragma unroll
        for (int i = 0; i < DIM / 8; ++i) {
            int ii = half * (DIM / 8) + i;     // this wave's 8 row-quads
            int row = 4 * ii + rq;
            float vr = __shfl(v, row, 64);
            vf4 val = {vr * pc0, vr * pc1, vr * pc2, vr * pc3};
            o4[row * (DIM / 4) + c] = val;
        }
    }
}

extern "C" void kernel_launch(void* const* d_in, const int* in_sizes, int n_in,
                              void* d_out, int out_size, void* d_ws, size_t ws_size,
                              hipStream_t stream) {
    const float* x = (const float*)d_in[0];   // (4096,) float32
    float* out = (float*)d_out;

    const int N = BATCH * DIM * DIM;
    const int interleaved = (out_size >= 2 * N) ? 1 : 0;

    // 2 waves per batch element -> 8192 waves -> 2048 blocks of 4 waves
    qencoder_kernel<<<BATCH * 2 / 4, 256, 0, stream>>>(x, out, interleaved);
}